// Round 10
// baseline (990.873 us; speedup 1.0000x reference)
//
#include <hip/hip_runtime.h>
#include <hip/hip_bf16.h>
#include <math.h>

#define T_SEQ 2048
#define D_MODEL 1024
#define NH 16
#define HD 64

// ---------------------------------------------------------------------------
// Kernel 1: QKV GEMM.  out[t][j] = sum_d x[t][d] * W[j][d]
// grid = (D/64, T/64, 3)  z: 0=Q, 1=K, 2=V (with lambda blend of vi)
// fp32 in, fp32 accumulate, fp32 out to workspace.
// ---------------------------------------------------------------------------
__global__ __launch_bounds__(256) void gemm_qkv(
        const float* __restrict__ x,
        const float* __restrict__ Wq, const float* __restrict__ Wk, const float* __restrict__ Wv,
        const float* __restrict__ vi, const float* __restrict__ lambdas,
        float* __restrict__ q, float* __restrict__ k, float* __restrict__ v)
{
    const int z = blockIdx.z;
    const float* __restrict__ W = (z == 0) ? Wq : (z == 1) ? Wk : Wv;
    float* __restrict__ out = (z == 0) ? q : (z == 1) ? k : v;

    const int row0 = blockIdx.y * 64;
    const int col0 = blockIdx.x * 64;

    __shared__ __align__(16) float As[32][68];
    __shared__ __align__(16) float Bs[32][68];

    const int tid = threadIdx.x;
    const int tx = tid & 15;
    const int ty = tid >> 4;

    float acc[4][4] = {};

    for (int k0 = 0; k0 < D_MODEL; k0 += 32) {
        __syncthreads();
        for (int i = tid; i < 1024; i += 256) {
            int r  = i >> 4;
            int c2 = i & 15;
            float2 u = ((const float2*)(x + (size_t)(row0 + r) * D_MODEL + k0))[c2];
            As[2 * c2][r]     = u.x;
            As[2 * c2 + 1][r] = u.y;
            float2 w2 = ((const float2*)(W + (size_t)(col0 + r) * D_MODEL + k0))[c2];
            Bs[2 * c2][r]     = w2.x;
            Bs[2 * c2 + 1][r] = w2.y;
        }
        __syncthreads();
        #pragma unroll
        for (int kk = 0; kk < 32; ++kk) {
            float4 a4 = *(const float4*)&As[kk][ty * 4];
            float4 b4 = *(const float4*)&Bs[kk][tx * 4];
            float a[4] = {a4.x, a4.y, a4.z, a4.w};
            float b[4] = {b4.x, b4.y, b4.z, b4.w};
            #pragma unroll
            for (int i = 0; i < 4; ++i)
                #pragma unroll
                for (int j = 0; j < 4; ++j)
                    acc[i][j] = fmaf(a[i], b[j], acc[i][j]);
        }
    }

    if (z == 2) {
        const float l0 = lambdas[0];
        const float l1 = lambdas[1];
        #pragma unroll
        for (int i = 0; i < 4; ++i)
            #pragma unroll
            for (int j = 0; j < 4; ++j) {
                size_t idx = (size_t)(row0 + ty * 4 + i) * D_MODEL + col0 + tx * 4 + j;
                out[idx] = l0 * acc[i][j] + l1 * vi[idx];
            }
    } else {
        #pragma unroll
        for (int i = 0; i < 4; ++i)
            #pragma unroll
            for (int j = 0; j < 4; ++j) {
                size_t idx = (size_t)(row0 + ty * 4 + i) * D_MODEL + col0 + tx * 4 + j;
                out[idx] = acc[i][j];
            }
    }
}

// ---------------------------------------------------------------------------
// Kernel 2: RMS norm (per t,h over hd=64) + rotary, in place on q and k.
// One wave per (t,h). Shown-source rotary sign (verified vs LDS variant).
// ---------------------------------------------------------------------------
__global__ __launch_bounds__(256) void norm_rope(float* __restrict__ q, float* __restrict__ k)
{
    const int w    = blockIdx.x * 4 + (threadIdx.x >> 6);
    const int lane = threadIdx.x & 63;
    const int t = w / NH;
    const int h = w % NH;
    const size_t base = (size_t)t * D_MODEL + h * HD + lane;

    const int j = lane & 31;
    const float f = (j < 16) ? exp2f(-10.0f * (float)j / 15.0f) : 0.0f;
    const float theta = (float)t * f;
    const float c = cosf(theta);
    const float s = sinf(theta);
    const float eps = 1.1920929e-7f;

    #pragma unroll
    for (int which = 0; which < 2; ++which) {
        float* __restrict__ p = which ? k : q;
        float val = p[base];
        float ss = val * val;
        #pragma unroll
        for (int off = 32; off > 0; off >>= 1) ss += __shfl_xor(ss, off);
        val *= rsqrtf(ss * (1.0f / 64.0f) + eps);
        float partner = __shfl_xor(val, 32);
        // lane<32: y1 = x1*c + x2*s ; lane>=32: y2 = -x1*s + x2*c
        float y = (lane < 32) ? (val * c + partner * s) : (val * c - partner * s);
        p[base] = y;
    }
}

// ---------------------------------------------------------------------------
// Kernel 3: causal flash attention. grid = (T/64, NH), block = 256.
// ---------------------------------------------------------------------------
__global__ __launch_bounds__(256) void attn(
        const float* __restrict__ q, const float* __restrict__ k,
        const float* __restrict__ v, float* __restrict__ y)
{
    const int h  = blockIdx.y;
    const int qt = blockIdx.x;
    const int t0 = qt * 64;

    __shared__ float Qs[64][65];
    __shared__ float KVs[64][65];
    __shared__ float Ss[64][65];
    __shared__ float m_s[64], l_s[64], alpha_s[64];

    const int tid = threadIdx.x;
    const int tx = tid & 15;
    const int ty = tid >> 4;

    for (int i = tid; i < 64 * 64; i += 256) {
        int r = i >> 6, c = i & 63;
        Qs[r][c] = q[(size_t)(t0 + r) * D_MODEL + h * HD + c];
    }
    if (tid < 64) { m_s[tid] = -1e30f; l_s[tid] = 0.0f; }

    float O[4][4] = {};

    for (int kt = 0; kt <= qt; ++kt) {
        const int s0 = kt * 64;
        __syncthreads();
        for (int i = tid; i < 64 * 64; i += 256) {
            int r = i >> 6, c = i & 63;
            KVs[r][c] = k[(size_t)(s0 + r) * D_MODEL + h * HD + c];
        }
        __syncthreads();

        float acc[4][4] = {};
        #pragma unroll 8
        for (int d = 0; d < 64; ++d) {
            float a[4], b[4];
            #pragma unroll
            for (int i = 0; i < 4; ++i) a[i] = Qs[ty * 4 + i][d];
            #pragma unroll
            for (int jj = 0; jj < 4; ++jj) b[jj] = KVs[tx * 4 + jj][d];
            #pragma unroll
            for (int i = 0; i < 4; ++i)
                #pragma unroll
                for (int jj = 0; jj < 4; ++jj)
                    acc[i][jj] = fmaf(a[i], b[jj], acc[i][jj]);
        }
        #pragma unroll
        for (int i = 0; i < 4; ++i)
            #pragma unroll
            for (int jj = 0; jj < 4; ++jj) {
                int m = t0 + ty * 4 + i;
                int n = s0 + tx * 4 + jj;
                float sv = acc[i][jj] * 0.125f;
                if (n > m) sv = -1e30f;
                Ss[ty * 4 + i][tx * 4 + jj] = sv;
            }
        __syncthreads();

        if (tid < 64) {
            float mo = m_s[tid];
            float mx = mo;
            for (int n = 0; n < 64; ++n) mx = fmaxf(mx, Ss[tid][n]);
            float al = __expf(mo - mx);
            float l = l_s[tid] * al;
            for (int n = 0; n < 64; ++n) {
                float p = __expf(Ss[tid][n] - mx);
                Ss[tid][n] = p;
                l += p;
            }
            m_s[tid] = mx; l_s[tid] = l; alpha_s[tid] = al;
        }
        __syncthreads();

        for (int i = tid; i < 64 * 64; i += 256) {
            int r = i >> 6, c = i & 63;
            KVs[r][c] = v[(size_t)(s0 + r) * D_MODEL + h * HD + c];
        }
        __syncthreads();

        float al4[4];
        #pragma unroll
        for (int i = 0; i < 4; ++i) al4[i] = alpha_s[ty * 4 + i];
        #pragma unroll
        for (int i = 0; i < 4; ++i)
            #pragma unroll
            for (int jj = 0; jj < 4; ++jj) O[i][jj] *= al4[i];

        #pragma unroll 8
        for (int n = 0; n < 64; ++n) {
            float p[4], vv[4];
            #pragma unroll
            for (int i = 0; i < 4; ++i) p[i] = Ss[ty * 4 + i][n];
            #pragma unroll
            for (int jj = 0; jj < 4; ++jj) vv[jj] = KVs[n][tx * 4 + jj];
            #pragma unroll
            for (int i = 0; i < 4; ++i)
                #pragma unroll
                for (int jj = 0; jj < 4; ++jj)
                    O[i][jj] = fmaf(p[i], vv[jj], O[i][jj]);
        }
    }

    #pragma unroll
    for (int i = 0; i < 4; ++i) {
        float inv_l = 1.0f / l_s[ty * 4 + i];
        #pragma unroll
        for (int jj = 0; jj < 4; ++jj) {
            y[(size_t)(t0 + ty * 4 + i) * D_MODEL + h * HD + tx * 4 + jj] = O[i][jj] * inv_l;
        }
    }
}

// ---------------------------------------------------------------------------
// Kernel 4: output projection. out[t][j] = sum_d y[t][d] * Wp[j][d].
// *** ROUND 10 CHANGE: out is FP32 (the reference's true output dtype). ***
// grid = (D/64, T/64)
// ---------------------------------------------------------------------------
__global__ __launch_bounds__(256) void gemm_proj(
        const float* __restrict__ A, const float* __restrict__ Wp, float* __restrict__ out)
{
    const int row0 = blockIdx.y * 64;
    const int col0 = blockIdx.x * 64;

    __shared__ __align__(16) float As[32][68];
    __shared__ __align__(16) float Bs[32][68];

    const int tid = threadIdx.x;
    const int tx = tid & 15;
    const int ty = tid >> 4;

    float acc[4][4] = {};

    for (int k0 = 0; k0 < D_MODEL; k0 += 32) {
        __syncthreads();
        for (int i = tid; i < 1024; i += 256) {
            int r  = i >> 4;
            int c2 = i & 15;
            float2 u = ((const float2*)(A + (size_t)(row0 + r) * D_MODEL + k0))[c2];
            As[2 * c2][r]     = u.x;
            As[2 * c2 + 1][r] = u.y;
            float2 w2 = ((const float2*)(Wp + (size_t)(col0 + r) * D_MODEL + k0))[c2];
            Bs[2 * c2][r]     = w2.x;
            Bs[2 * c2 + 1][r] = w2.y;
        }
        __syncthreads();
        #pragma unroll
        for (int kk = 0; kk < 32; ++kk) {
            float4 a4 = *(const float4*)&As[kk][ty * 4];
            float4 b4 = *(const float4*)&Bs[kk][tx * 4];
            float a[4] = {a4.x, a4.y, a4.z, a4.w};
            float b[4] = {b4.x, b4.y, b4.z, b4.w};
            #pragma unroll
            for (int i = 0; i < 4; ++i)
                #pragma unroll
                for (int j = 0; j < 4; ++j)
                    acc[i][j] = fmaf(a[i], b[j], acc[i][j]);
        }
    }

    #pragma unroll
    for (int i = 0; i < 4; ++i)
        #pragma unroll
        for (int j = 0; j < 4; ++j) {
            size_t idx = (size_t)(row0 + ty * 4 + i) * D_MODEL + col0 + tx * 4 + j;
            out[idx] = acc[i][j];
        }
}

// ---------------------------------------------------------------------------
extern "C" void kernel_launch(void* const* d_in, const int* in_sizes, int n_in,
                              void* d_out, int out_size, void* d_ws, size_t ws_size,
                              hipStream_t stream) {
    (void)in_sizes; (void)n_in; (void)out_size; (void)ws_size;
    const float* x   = (const float*)d_in[0];
    const float* vi  = (const float*)d_in[1];
    const float* Wq  = (const float*)d_in[2];
    const float* Wk  = (const float*)d_in[3];
    const float* Wv  = (const float*)d_in[4];
    const float* Wp  = (const float*)d_in[5];
    const float* lam = (const float*)d_in[6];

    const size_t TD = (size_t)T_SEQ * D_MODEL;
    float* q = (float*)d_ws;
    float* k = q + TD;
    float* v = k + TD;
    float* y = v + TD;
    float* out = (float*)d_out;   // fp32 output — reference returns float32

    gemm_qkv<<<dim3(D_MODEL / 64, T_SEQ / 64, 3), 256, 0, stream>>>(x, Wq, Wk, Wv, vi, lam, q, k, v);
    norm_rope<<<dim3(T_SEQ * NH / 4), 256, 0, stream>>>(q, k);
    attn<<<dim3(T_SEQ / 64, NH), 256, 0, stream>>>(q, k, v, y);
    gemm_proj<<<dim3(D_MODEL / 64, T_SEQ / 64), 256, 0, stream>>>(y, Wp, out);
}

// Round 11
// 245.967 us; speedup vs baseline: 4.0285x; 4.0285x over previous
//
#include <hip/hip_runtime.h>
#include <math.h>

#define T_SEQ 2048
#define D_MODEL 1024
#define NH 16
#define HD 64

typedef unsigned short ushort_t;
typedef unsigned int uint_t;
typedef short short8 __attribute__((ext_vector_type(8)));
typedef float floatx4 __attribute__((ext_vector_type(4)));

// ---- bf16 helpers (RNE) ----
__device__ __forceinline__ ushort_t f2bf(float f) {
    uint_t u = __float_as_uint(f);
    u += 0x7FFFu + ((u >> 16) & 1u);
    return (ushort_t)(u >> 16);
}
__device__ __forceinline__ uint_t pack2(float a, float b) {
    return (uint_t)f2bf(a) | ((uint_t)f2bf(b) << 16);
}
// 16 fp32 (16B-aligned) -> 16 bf16 at LDS dst (16B-aligned)
__device__ __forceinline__ void cvt16(ushort_t* dst, const float* src) {
    float4 f0 = ((const float4*)src)[0];
    float4 f1 = ((const float4*)src)[1];
    float4 f2 = ((const float4*)src)[2];
    float4 f3 = ((const float4*)src)[3];
    uint4 a, b;
    a.x = pack2(f0.x, f0.y); a.y = pack2(f0.z, f0.w);
    a.z = pack2(f1.x, f1.y); a.w = pack2(f1.z, f1.w);
    b.x = pack2(f2.x, f2.y); b.y = pack2(f2.z, f2.w);
    b.z = pack2(f3.x, f3.y); b.w = pack2(f3.z, f3.w);
    ((uint4*)dst)[0] = a;
    ((uint4*)dst)[1] = b;
}
// copy 16 bf16 (32B) global -> LDS
__device__ __forceinline__ void cp16(ushort_t* dst, const ushort_t* src) {
    uint4 a = ((const uint4*)src)[0];
    uint4 b = ((const uint4*)src)[1];
    ((uint4*)dst)[0] = a;
    ((uint4*)dst)[1] = b;
}

#define LDA 40   // GEMM LDS row stride (ushorts): 32 k + 8 pad = 80 B (16B-aligned, conflict-free frags)
#define LDK 72   // attn LDS row stride (ushorts): 64 + 8 pad = 144 B (16B-aligned)

// ---------------------------------------------------------------------------
// Kernel 1: QKV GEMM via bf16 MFMA. C = x(2048xK) * W(NxK)^T, K=N=1024.
// grid=(8,16,3) block=256 (4 waves, each a 64x64 quadrant of the 128x128 tile).
// z=0: q32 fp32; z=1: k32 fp32; z=2: lambda blend with vi -> vbt bf16 [j][t].
// ---------------------------------------------------------------------------
__global__ __launch_bounds__(256) void gemm_qkv(
        const float* __restrict__ x,
        const float* __restrict__ Wq, const float* __restrict__ Wk, const float* __restrict__ Wv,
        const float* __restrict__ vi, const float* __restrict__ lam,
        float* __restrict__ q32, float* __restrict__ k32, ushort_t* __restrict__ vbt)
{
    const int z = blockIdx.z;
    const float* __restrict__ W = (z == 0) ? Wq : (z == 1) ? Wk : Wv;
    const int row0 = blockIdx.y * 128;
    const int col0 = blockIdx.x * 128;

    __shared__ ushort_t As[128 * LDA];
    __shared__ ushort_t Bs[128 * LDA];

    const int tid = threadIdx.x;
    const int wave = tid >> 6, lane = tid & 63;
    const int wm = wave >> 1, wn = wave & 1;
    const int l15 = lane & 15, quad = lane >> 4;
    const int r_st = tid >> 1;            // staging row 0..127
    const int c_st = (tid & 1) * 16;      // staging k-offset 0/16

    floatx4 acc[4][4];
    #pragma unroll
    for (int i = 0; i < 4; ++i)
        #pragma unroll
        for (int j = 0; j < 4; ++j)
            acc[i][j] = (floatx4){0.f, 0.f, 0.f, 0.f};

    for (int k0 = 0; k0 < D_MODEL; k0 += 32) {
        __syncthreads();
        cvt16(As + r_st * LDA + c_st, x + (size_t)(row0 + r_st) * D_MODEL + k0 + c_st);
        cvt16(Bs + r_st * LDA + c_st, W + (size_t)(col0 + r_st) * D_MODEL + k0 + c_st);
        __syncthreads();
        short8 a[4], b[4];
        #pragma unroll
        for (int i = 0; i < 4; ++i) {
            a[i] = *(const short8*)(As + (64 * wm + i * 16 + l15) * LDA + quad * 8);
            b[i] = *(const short8*)(Bs + (64 * wn + i * 16 + l15) * LDA + quad * 8);
        }
        #pragma unroll
        for (int i = 0; i < 4; ++i)
            #pragma unroll
            for (int j = 0; j < 4; ++j)
                acc[i][j] = __builtin_amdgcn_mfma_f32_16x16x32_bf16(a[i], b[j], acc[i][j], 0, 0, 0);
    }

    // C-layout: col=lane&15, row=quad*4+reg
    if (z < 2) {
        float* __restrict__ o = (z == 0) ? q32 : k32;
        #pragma unroll
        for (int i = 0; i < 4; ++i)
            #pragma unroll
            for (int j = 0; j < 4; ++j) {
                const int t = row0 + 64 * wm + i * 16 + quad * 4;
                const int jj = col0 + 64 * wn + j * 16 + l15;
                #pragma unroll
                for (int r = 0; r < 4; ++r)
                    o[(size_t)(t + r) * D_MODEL + jj] = acc[i][j][r];
            }
    } else {
        const float l0 = lam[0], l1 = lam[1];
        #pragma unroll
        for (int i = 0; i < 4; ++i)
            #pragma unroll
            for (int j = 0; j < 4; ++j) {
                const int t = row0 + 64 * wm + i * 16 + quad * 4;
                const int jj = col0 + 64 * wn + j * 16 + l15;
                #pragma unroll
                for (int r = 0; r < 4; ++r) {
                    float vv = l0 * acc[i][j][r] + l1 * vi[(size_t)(t + r) * D_MODEL + jj];
                    vbt[(size_t)jj * T_SEQ + (t + r)] = f2bf(vv);   // transposed [d_model_col][t]
                }
            }
    }
}

// ---------------------------------------------------------------------------
// Kernel 2: RMS norm + rotary. Reads fp32 q/k, writes bf16 qb (pre-scaled by
// 1/8 = 1/sqrt(hd)) and kb. One wave per (t,h).
// ---------------------------------------------------------------------------
__global__ __launch_bounds__(256) void norm_rope(
        const float* __restrict__ q32, const float* __restrict__ k32,
        ushort_t* __restrict__ qb, ushort_t* __restrict__ kb)
{
    const int w    = blockIdx.x * 4 + (threadIdx.x >> 6);
    const int lane = threadIdx.x & 63;
    const int t = w / NH;
    const int h = w % NH;
    const size_t base = (size_t)t * D_MODEL + h * HD + lane;

    const int j = lane & 31;
    const float f = (j < 16) ? exp2f(-10.0f * (float)j / 15.0f) : 0.0f;
    const float theta = (float)t * f;
    const float c = cosf(theta);
    const float s = sinf(theta);
    const float eps = 1.1920929e-7f;

    {
        float val = q32[base];
        float ss = val * val;
        #pragma unroll
        for (int off = 32; off > 0; off >>= 1) ss += __shfl_xor(ss, off);
        val *= rsqrtf(ss * (1.0f / 64.0f) + eps);
        float partner = __shfl_xor(val, 32);
        float y = (lane < 32) ? (val * c + partner * s) : (val * c - partner * s);
        qb[base] = f2bf(y * 0.125f);    // fold 1/sqrt(hd)
    }
    {
        float val = k32[base];
        float ss = val * val;
        #pragma unroll
        for (int off = 32; off > 0; off >>= 1) ss += __shfl_xor(ss, off);
        val *= rsqrtf(ss * (1.0f / 64.0f) + eps);
        float partner = __shfl_xor(val, 32);
        float y = (lane < 32) ? (val * c + partner * s) : (val * c - partner * s);
        kb[base] = f2bf(y);
    }
}

// ---------------------------------------------------------------------------
// Kernel 3: MFMA flash attention. grid=(32 qt reversed, 16 h), block=256.
// Per block: 64 q-rows of one head; each wave owns a 16-row stripe.
// S=Q*K^T (MFMA), register online-softmax in C-layout, P->LDS (wave-private
// stripe, no extra barrier), O+=P*V (MFMA, V pre-transposed [d][t]).
// ---------------------------------------------------------------------------
__global__ __launch_bounds__(256) void attn(
        const ushort_t* __restrict__ qb, const ushort_t* __restrict__ kb,
        const ushort_t* __restrict__ vbt, ushort_t* __restrict__ yb)
{
    const int h  = blockIdx.y;
    const int qt = (int)gridDim.x - 1 - blockIdx.x;   // big blocks first
    const int t0 = qt * 64;

    __shared__ ushort_t Ks[64 * LDK];    // [s][d]
    __shared__ ushort_t Vs[64 * LDK];    // [d][s]  (from pre-transposed vbt)
    __shared__ ushort_t QPs[64 * LDK];   // Q tile, then reused for P

    const int tid = threadIdx.x;
    const int wave = tid >> 6, lane = tid & 63;
    const int l15 = lane & 15, quad = lane >> 4;
    const int r_st = tid >> 2;           // staging row 0..63
    const int c_st = (tid & 3) * 16;     // staging col 0/16/32/48

    // stage Q tile, load A-frags (resident whole kernel)
    cp16(QPs + r_st * LDK + c_st, qb + (size_t)(t0 + r_st) * D_MODEL + h * HD + c_st);
    __syncthreads();
    short8 qf[2];
    qf[0] = *(const short8*)(QPs + (16 * wave + l15) * LDK + 0  + quad * 8);
    qf[1] = *(const short8*)(QPs + (16 * wave + l15) * LDK + 32 + quad * 8);

    float m_run[4], l_run[4];
    floatx4 O[4];
    #pragma unroll
    for (int r = 0; r < 4; ++r) { m_run[r] = -1e30f; l_run[r] = 0.0f; }
    #pragma unroll
    for (int d = 0; d < 4; ++d) O[d] = (floatx4){0.f, 0.f, 0.f, 0.f};

    for (int kt = 0; kt <= qt; ++kt) {
        const int s0 = kt * 64;
        __syncthreads();   // prev iter's MFMA reads done before restage
        cp16(Ks + r_st * LDK + c_st, kb  + (size_t)(s0 + r_st) * D_MODEL + h * HD + c_st);
        cp16(Vs + r_st * LDK + c_st, vbt + (size_t)(h * HD + r_st) * T_SEQ + s0 + c_st);
        __syncthreads();

        // S stripe (16 x 64): 4 col-tiles x 2 k-steps
        floatx4 sa[4];
        #pragma unroll
        for (int ct = 0; ct < 4; ++ct) {
            short8 b0 = *(const short8*)(Ks + (ct * 16 + l15) * LDK + 0  + quad * 8);
            short8 b1 = *(const short8*)(Ks + (ct * 16 + l15) * LDK + 32 + quad * 8);
            floatx4 t4 = (floatx4){0.f, 0.f, 0.f, 0.f};
            t4 = __builtin_amdgcn_mfma_f32_16x16x32_bf16(qf[0], b0, t4, 0, 0, 0);
            t4 = __builtin_amdgcn_mfma_f32_16x16x32_bf16(qf[1], b1, t4, 0, 0, 0);
            sa[ct] = t4;
        }
        if (kt == qt) {   // causal mask on the diagonal tile
            #pragma unroll
            for (int ct = 0; ct < 4; ++ct)
                #pragma unroll
                for (int r = 0; r < 4; ++r) {
                    int trow = 16 * wave + quad * 4 + r;
                    int scol = ct * 16 + l15;
                    if (scol > trow) sa[ct][r] = -1e30f;
                }
        }
        // register online-softmax (rows = quad*4+r, cols across 16 lanes of quad)
        float mx[4], alpha[4], rs[4];
        #pragma unroll
        for (int r = 0; r < 4; ++r) {
            float m0 = fmaxf(fmaxf(sa[0][r], sa[1][r]), fmaxf(sa[2][r], sa[3][r]));
            #pragma unroll
            for (int msk = 1; msk <= 8; msk <<= 1) m0 = fmaxf(m0, __shfl_xor(m0, msk));
            float mn = fmaxf(m_run[r], m0);
            alpha[r] = __expf(m_run[r] - mn);
            m_run[r] = mn;
            rs[r] = 0.0f;
        }
        float p[4][4];
        #pragma unroll
        for (int ct = 0; ct < 4; ++ct)
            #pragma unroll
            for (int r = 0; r < 4; ++r) {
                p[ct][r] = __expf(sa[ct][r] - m_run[r]);
                rs[r] += p[ct][r];
            }
        #pragma unroll
        for (int r = 0; r < 4; ++r) {
            #pragma unroll
            for (int msk = 1; msk <= 8; msk <<= 1) rs[r] += __shfl_xor(rs[r], msk);
            l_run[r] = l_run[r] * alpha[r] + rs[r];
        }
        #pragma unroll
        for (int d = 0; d < 4; ++d)
            #pragma unroll
            for (int r = 0; r < 4; ++r) O[d][r] *= alpha[r];

        // P -> LDS (own 16-row stripe; wave-internal LDS order => no barrier)
        #pragma unroll
        for (int ct = 0; ct < 4; ++ct)
            #pragma unroll
            for (int r = 0; r < 4; ++r)
                QPs[(16 * wave + quad * 4 + r) * LDK + ct * 16 + l15] = f2bf(p[ct][r]);

        // O += P * V : A-frags from own P stripe, B-frags from Vs[d][s]
        short8 pa0 = *(const short8*)(QPs + (16 * wave + l15) * LDK + 0  + quad * 8);
        short8 pa1 = *(const short8*)(QPs + (16 * wave + l15) * LDK + 32 + quad * 8);
        #pragma unroll
        for (int dt = 0; dt < 4; ++dt) {
            short8 vb0 = *(const short8*)(Vs + (dt * 16 + l15) * LDK + 0  + quad * 8);
            short8 vb1 = *(const short8*)(Vs + (dt * 16 + l15) * LDK + 32 + quad * 8);
            O[dt] = __builtin_amdgcn_mfma_f32_16x16x32_bf16(pa0, vb0, O[dt], 0, 0, 0);
            O[dt] = __builtin_amdgcn_mfma_f32_16x16x32_bf16(pa1, vb1, O[dt], 0, 0, 0);
        }
    }

    #pragma unroll
    for (int r = 0; r < 4; ++r) {
        const float inv_l = 1.0f / l_run[r];
        const int t = t0 + 16 * wave + quad * 4 + r;
        #pragma unroll
        for (int dt = 0; dt < 4; ++dt)
            yb[(size_t)t * D_MODEL + h * HD + dt * 16 + l15] = f2bf(O[dt][r] * inv_l);
    }
}

// ---------------------------------------------------------------------------
// Kernel 4: output projection via bf16 MFMA. A = yb bf16, B = Wp fp32 (cvt in
// staging), C = fp32 d_out. grid=(8,16), block=256.
// ---------------------------------------------------------------------------
__global__ __launch_bounds__(256) void gemm_proj(
        const ushort_t* __restrict__ yb, const float* __restrict__ Wp,
        float* __restrict__ out)
{
    const int row0 = blockIdx.y * 128;
    const int col0 = blockIdx.x * 128;

    __shared__ ushort_t As[128 * LDA];
    __shared__ ushort_t Bs[128 * LDA];

    const int tid = threadIdx.x;
    const int wave = tid >> 6, lane = tid & 63;
    const int wm = wave >> 1, wn = wave & 1;
    const int l15 = lane & 15, quad = lane >> 4;
    const int r_st = tid >> 1;
    const int c_st = (tid & 1) * 16;

    floatx4 acc[4][4];
    #pragma unroll
    for (int i = 0; i < 4; ++i)
        #pragma unroll
        for (int j = 0; j < 4; ++j)
            acc[i][j] = (floatx4){0.f, 0.f, 0.f, 0.f};

    for (int k0 = 0; k0 < D_MODEL; k0 += 32) {
        __syncthreads();
        cp16(As + r_st * LDA + c_st, yb + (size_t)(row0 + r_st) * D_MODEL + k0 + c_st);
        cvt16(Bs + r_st * LDA + c_st, Wp + (size_t)(col0 + r_st) * D_MODEL + k0 + c_st);
        __syncthreads();
        short8 a[4], b[4];
        #pragma unroll
        for (int i = 0; i < 4; ++i) {
            a[i] = *(const short8*)(As + (64 * wm + i * 16 + l15) * LDA + quad * 8);
            b[i] = *(const short8*)(Bs + (64 * wn + i * 16 + l15) * LDA + quad * 8);
        }
        #pragma unroll
        for (int i = 0; i < 4; ++i)
            #pragma unroll
            for (int j = 0; j < 4; ++j)
                acc[i][j] = __builtin_amdgcn_mfma_f32_16x16x32_bf16(a[i], b[j], acc[i][j], 0, 0, 0);
    }

    #pragma unroll
    for (int i = 0; i < 4; ++i)
        #pragma unroll
        for (int j = 0; j < 4; ++j) {
            const int t = row0 + 64 * wm + i * 16 + quad * 4;
            const int jj = col0 + 64 * wn + j * 16 + l15;
            #pragma unroll
            for (int r = 0; r < 4; ++r)
                out[(size_t)(t + r) * D_MODEL + jj] = acc[i][j][r];
        }
}

// ---------------------------------------------------------------------------
extern "C" void kernel_launch(void* const* d_in, const int* in_sizes, int n_in,
                              void* d_out, int out_size, void* d_ws, size_t ws_size,
                              hipStream_t stream) {
    (void)in_sizes; (void)n_in; (void)out_size; (void)ws_size;
    const float* x   = (const float*)d_in[0];
    const float* vi  = (const float*)d_in[1];
    const float* Wq  = (const float*)d_in[2];
    const float* Wk  = (const float*)d_in[3];
    const float* Wv  = (const float*)d_in[4];
    const float* Wp  = (const float*)d_in[5];
    const float* lam = (const float*)d_in[6];

    char* base = (char*)d_ws;                               // 32 MiB total
    float*    q32 = (float*)(base);                         // [ 0, 8) MiB
    float*    k32 = (float*)(base + (size_t)8  * 1048576);  // [ 8,16)
    ushort_t* qb  = (ushort_t*)(base + (size_t)16 * 1048576); // [16,20)
    ushort_t* kb  = (ushort_t*)(base + (size_t)20 * 1048576); // [20,24)
    ushort_t* vbt = (ushort_t*)(base + (size_t)24 * 1048576); // [24,28)  [d][t]
    ushort_t* yb  = (ushort_t*)(base + (size_t)28 * 1048576); // [28,32)
    float* out = (float*)d_out;

    gemm_qkv<<<dim3(8, 16, 3), 256, 0, stream>>>(x, Wq, Wk, Wv, vi, lam, q32, k32, vbt);
    norm_rope<<<dim3(T_SEQ * NH / 4), 256, 0, stream>>>(q32, k32, qb, kb);
    attn<<<dim3(32, 16), 256, 0, stream>>>(qb, kb, vbt, yb);
    gemm_proj<<<dim3(8, 16), 256, 0, stream>>>(yb, Wp, out);
}

// Round 12
// 200.766 us; speedup vs baseline: 4.9355x; 1.2251x over previous
//
#include <hip/hip_runtime.h>
#include <math.h>

#define T_SEQ 2048
#define D_MODEL 1024
#define NH 16
#define HD 64

typedef unsigned short ushort_t;
typedef unsigned int uint_t;
typedef short short8 __attribute__((ext_vector_type(8)));
typedef float floatx4 __attribute__((ext_vector_type(4)));

// ---- bf16 helpers (RNE) ----
__device__ __forceinline__ ushort_t f2bf(float f) {
    uint_t u = __float_as_uint(f);
    u += 0x7FFFu + ((u >> 16) & 1u);
    return (ushort_t)(u >> 16);
}
__device__ __forceinline__ uint_t pack2(float a, float b) {
    return (uint_t)f2bf(a) | ((uint_t)f2bf(b) << 16);
}
// copy 16 bf16 (32B) global/LDS
__device__ __forceinline__ void cp16(ushort_t* dst, const ushort_t* src) {
    uint4 a = ((const uint4*)src)[0];
    uint4 b = ((const uint4*)src)[1];
    ((uint4*)dst)[0] = a;
    ((uint4*)dst)[1] = b;
}

#define LDB 72    // GEMM LDS row stride (ushorts): 64 + 8 pad (16B-aligned, 2-way max)
#define LDK 72    // attn K/Q/P row stride (64 cols)
#define LDV 136   // attn V row stride (128 cols + 8 pad)

// ---------------------------------------------------------------------------
// Kernel 0: one-time fp32 -> bf16 convert of x, Wq, Wk, Wv, Wp.
// unit = 8 elements; totals: x 262144, each W 131072 units.
// ---------------------------------------------------------------------------
__global__ __launch_bounds__(256) void to_bf16(
        const float* __restrict__ x,  const float* __restrict__ wq,
        const float* __restrict__ wk, const float* __restrict__ wv,
        const float* __restrict__ wp,
        ushort_t* __restrict__ xb,  ushort_t* __restrict__ wqb,
        ushort_t* __restrict__ wkb, ushort_t* __restrict__ wvb,
        ushort_t* __restrict__ wpb)
{
    size_t i = (size_t)blockIdx.x * 256 + threadIdx.x;
    const float* src; ushort_t* dst; size_t off;
    if (i < 262144)      { src = x;  dst = xb;  off = i; }
    else if (i < 393216) { src = wq; dst = wqb; off = i - 262144; }
    else if (i < 524288) { src = wk; dst = wkb; off = i - 393216; }
    else if (i < 655360) { src = wv; dst = wvb; off = i - 524288; }
    else                 { src = wp; dst = wpb; off = i - 655360; }
    float4 f0 = ((const float4*)src)[off * 2];
    float4 f1 = ((const float4*)src)[off * 2 + 1];
    uint4 u;
    u.x = pack2(f0.x, f0.y); u.y = pack2(f0.z, f0.w);
    u.z = pack2(f1.x, f1.y); u.w = pack2(f1.z, f1.w);
    ((uint4*)dst)[off] = u;
}

// ---------------------------------------------------------------------------
// Kernel 1: QKV GEMM (bf16 MFMA, BK=64) with FUSED RMSNorm+RoPE epilogue.
// grid=(8,16,3) block=256. z=0 -> qb (pre-scaled 1/8), z=1 -> kb,
// z=2 -> lambda blend with vi -> vbt bf16 transposed [d][t].
// Each wave owns a 64x64 quadrant = exactly one head's columns.
// ---------------------------------------------------------------------------
__global__ __launch_bounds__(256) void gemm_qkv(
        const ushort_t* __restrict__ xb,
        const ushort_t* __restrict__ Wqb, const ushort_t* __restrict__ Wkb,
        const ushort_t* __restrict__ Wvb,
        const float* __restrict__ vi, const float* __restrict__ lam,
        ushort_t* __restrict__ qb, ushort_t* __restrict__ kb,
        ushort_t* __restrict__ vbt)
{
    const int z = blockIdx.z;
    const ushort_t* __restrict__ W = (z == 0) ? Wqb : (z == 1) ? Wkb : Wvb;
    const int row0 = blockIdx.y * 128;
    const int col0 = blockIdx.x * 128;

    __shared__ ushort_t As[128 * LDB];
    __shared__ ushort_t Bs[128 * LDB];

    const int tid = threadIdx.x;
    const int wave = tid >> 6, lane = tid & 63;
    const int wm = wave >> 1, wn = wave & 1;
    const int l15 = lane & 15, quad = lane >> 4;
    const int r_st = tid >> 1;            // staging row 0..127
    const int c_st = (tid & 1) * 32;      // staging col 0/32

    floatx4 acc[4][4];
    #pragma unroll
    for (int i = 0; i < 4; ++i)
        #pragma unroll
        for (int j = 0; j < 4; ++j)
            acc[i][j] = (floatx4){0.f, 0.f, 0.f, 0.f};

    for (int k0 = 0; k0 < D_MODEL; k0 += 64) {
        __syncthreads();
        cp16(As + r_st * LDB + c_st,      xb + (size_t)(row0 + r_st) * D_MODEL + k0 + c_st);
        cp16(As + r_st * LDB + c_st + 16, xb + (size_t)(row0 + r_st) * D_MODEL + k0 + c_st + 16);
        cp16(Bs + r_st * LDB + c_st,      W  + (size_t)(col0 + r_st) * D_MODEL + k0 + c_st);
        cp16(Bs + r_st * LDB + c_st + 16, W  + (size_t)(col0 + r_st) * D_MODEL + k0 + c_st + 16);
        __syncthreads();
        #pragma unroll
        for (int kh = 0; kh < 2; ++kh) {
            short8 a[4], b[4];
            #pragma unroll
            for (int i = 0; i < 4; ++i) {
                a[i] = *(const short8*)(As + (64 * wm + i * 16 + l15) * LDB + kh * 32 + quad * 8);
                b[i] = *(const short8*)(Bs + (64 * wn + i * 16 + l15) * LDB + kh * 32 + quad * 8);
            }
            #pragma unroll
            for (int i = 0; i < 4; ++i)
                #pragma unroll
                for (int j = 0; j < 4; ++j)
                    acc[i][j] = __builtin_amdgcn_mfma_f32_16x16x32_bf16(a[i], b[j], acc[i][j], 0, 0, 0);
        }
    }

    if (z < 2) {
        // Fused RMSNorm + RoPE. This wave's cols (col0+64*wn .. +63) = one head.
        ushort_t* __restrict__ o = (z == 0) ? qb : kb;
        const float oscale = (z == 0) ? 0.125f : 1.0f;   // fold 1/sqrt(hd) into q
        const int hbase = col0 + 64 * wn;
        const float eps = 1.1920929e-7f;
        const float fr = exp2f(-10.0f * (float)l15 / 15.0f);  // rotating-pair freq
        #pragma unroll
        for (int i = 0; i < 4; ++i)
            #pragma unroll
            for (int r = 0; r < 4; ++r) {
                const int t = row0 + 64 * wm + i * 16 + quad * 4 + r;
                float v0 = acc[i][0][r], v1 = acc[i][1][r];
                float v2 = acc[i][2][r], v3 = acc[i][3][r];
                float ss = v0 * v0 + v1 * v1 + v2 * v2 + v3 * v3;
                ss += __shfl_xor(ss, 1);
                ss += __shfl_xor(ss, 2);
                ss += __shfl_xor(ss, 4);
                ss += __shfl_xor(ss, 8);
                const float sc = rsqrtf(ss * (1.0f / 64.0f) + eps);
                v0 *= sc; v1 *= sc; v2 *= sc; v3 *= sc;
                const float th = (float)t * fr;
                const float cs = cosf(th), sn = sinf(th);
                const float y0 = v0 * cs + v2 * sn;   // shown-source rotary sign
                const float y2 = v2 * cs - v0 * sn;
                const size_t rb = (size_t)t * D_MODEL + hbase;
                o[rb +  0 + l15] = f2bf(y0 * oscale);
                o[rb + 16 + l15] = f2bf(v1 * oscale);
                o[rb + 32 + l15] = f2bf(y2 * oscale);
                o[rb + 48 + l15] = f2bf(v3 * oscale);
            }
    } else {
        const float l0 = lam[0], l1 = lam[1];
        #pragma unroll
        for (int i = 0; i < 4; ++i)
            #pragma unroll
            for (int j = 0; j < 4; ++j) {
                const int tb = row0 + 64 * wm + i * 16 + quad * 4;
                const int jj = col0 + 64 * wn + j * 16 + l15;
                float b0 = l0 * acc[i][j][0] + l1 * vi[(size_t)(tb + 0) * D_MODEL + jj];
                float b1 = l0 * acc[i][j][1] + l1 * vi[(size_t)(tb + 1) * D_MODEL + jj];
                float b2 = l0 * acc[i][j][2] + l1 * vi[(size_t)(tb + 2) * D_MODEL + jj];
                float b3 = l0 * acc[i][j][3] + l1 * vi[(size_t)(tb + 3) * D_MODEL + jj];
                uint2 u;
                u.x = pack2(b0, b1);
                u.y = pack2(b2, b3);
                *(uint2*)(vbt + (size_t)jj * T_SEQ + tb) = u;   // [d][t]
            }
    }
}

// ---------------------------------------------------------------------------
// Kernel 2: MFMA flash attention, BK=128 (two 64-wide K/V tiles per barrier
// pair). grid=(32 qt reversed, 16 h), block=256; each wave owns a 16-row
// q stripe. Register online-softmax in C-layout; P->LDS wave-private.
// ---------------------------------------------------------------------------
__global__ __launch_bounds__(256) void attn(
        const ushort_t* __restrict__ qb, const ushort_t* __restrict__ kb,
        const ushort_t* __restrict__ vbt, ushort_t* __restrict__ yb)
{
    const int h  = blockIdx.y;
    const int qt = (int)gridDim.x - 1 - blockIdx.x;   // big blocks first
    const int t0 = qt * 64;

    __shared__ ushort_t Ks[128 * LDK];   // [s_local 0..127][d]
    __shared__ ushort_t Vs[64 * LDV];    // [d][s_local 0..127]
    __shared__ ushort_t QPs[64 * LDK];   // Q tile, then reused for P

    const int tid = threadIdx.x;
    const int wave = tid >> 6, lane = tid & 63;
    const int l15 = lane & 15, quad = lane >> 4;

    // stage Q (64x64)
    {
        const int r4 = tid >> 2, c4 = (tid & 3) * 16;
        cp16(QPs + r4 * LDK + c4, qb + (size_t)(t0 + r4) * D_MODEL + h * HD + c4);
    }
    __syncthreads();
    short8 qf[2];
    qf[0] = *(const short8*)(QPs + (16 * wave + l15) * LDK + 0  + quad * 8);
    qf[1] = *(const short8*)(QPs + (16 * wave + l15) * LDK + 32 + quad * 8);

    float m_run[4], l_run[4];
    floatx4 O[4];
    #pragma unroll
    for (int r = 0; r < 4; ++r) { m_run[r] = -1e30f; l_run[r] = 0.0f; }
    #pragma unroll
    for (int d = 0; d < 4; ++d) O[d] = (floatx4){0.f, 0.f, 0.f, 0.f};

    for (int kt0 = 0; kt0 <= qt; kt0 += 2) {
        const int s0 = kt0 * 64;
        __syncthreads();
        {   // stage K: 128 rows x 64 cols
            const int r2 = tid >> 1, c2 = (tid & 1) * 32;
            cp16(Ks + r2 * LDK + c2,      kb + (size_t)(s0 + r2) * D_MODEL + h * HD + c2);
            cp16(Ks + r2 * LDK + c2 + 16, kb + (size_t)(s0 + r2) * D_MODEL + h * HD + c2 + 16);
            // stage V: 64 rows (d) x 128 cols (s)
            const int r4 = tid >> 2, c4 = (tid & 3) * 32;
            cp16(Vs + r4 * LDV + c4,      vbt + (size_t)(h * HD + r4) * T_SEQ + s0 + c4);
            cp16(Vs + r4 * LDV + c4 + 16, vbt + (size_t)(h * HD + r4) * T_SEQ + s0 + c4 + 16);
        }
        __syncthreads();

        const int ktend = (kt0 + 1 <= qt) ? 2 : 1;
        for (int sub = 0; sub < ktend; ++sub) {
            const int kt = kt0 + sub;
            const int sl = sub * 64;             // local s offset in LDS

            floatx4 sa[4];
            #pragma unroll
            for (int ct = 0; ct < 4; ++ct) {
                short8 b0 = *(const short8*)(Ks + (sl + ct * 16 + l15) * LDK + 0  + quad * 8);
                short8 b1 = *(const short8*)(Ks + (sl + ct * 16 + l15) * LDK + 32 + quad * 8);
                floatx4 t4 = (floatx4){0.f, 0.f, 0.f, 0.f};
                t4 = __builtin_amdgcn_mfma_f32_16x16x32_bf16(qf[0], b0, t4, 0, 0, 0);
                t4 = __builtin_amdgcn_mfma_f32_16x16x32_bf16(qf[1], b1, t4, 0, 0, 0);
                sa[ct] = t4;
            }
            if (kt == qt) {   // causal mask on the diagonal tile
                #pragma unroll
                for (int ct = 0; ct < 4; ++ct)
                    #pragma unroll
                    for (int r = 0; r < 4; ++r) {
                        int trow = 16 * wave + quad * 4 + r;
                        int scol = ct * 16 + l15;
                        if (scol > trow) sa[ct][r] = -1e30f;
                    }
            }
            // register online-softmax
            float alpha[4], rs[4];
            #pragma unroll
            for (int r = 0; r < 4; ++r) {
                float m0 = fmaxf(fmaxf(sa[0][r], sa[1][r]), fmaxf(sa[2][r], sa[3][r]));
                m0 = fmaxf(m0, __shfl_xor(m0, 1));
                m0 = fmaxf(m0, __shfl_xor(m0, 2));
                m0 = fmaxf(m0, __shfl_xor(m0, 4));
                m0 = fmaxf(m0, __shfl_xor(m0, 8));
                float mn = fmaxf(m_run[r], m0);
                alpha[r] = __expf(m_run[r] - mn);
                m_run[r] = mn;
                rs[r] = 0.0f;
            }
            float p[4][4];
            #pragma unroll
            for (int ct = 0; ct < 4; ++ct)
                #pragma unroll
                for (int r = 0; r < 4; ++r) {
                    p[ct][r] = __expf(sa[ct][r] - m_run[r]);
                    rs[r] += p[ct][r];
                }
            #pragma unroll
            for (int r = 0; r < 4; ++r) {
                rs[r] += __shfl_xor(rs[r], 1);
                rs[r] += __shfl_xor(rs[r], 2);
                rs[r] += __shfl_xor(rs[r], 4);
                rs[r] += __shfl_xor(rs[r], 8);
                l_run[r] = l_run[r] * alpha[r] + rs[r];
            }
            #pragma unroll
            for (int d = 0; d < 4; ++d)
                #pragma unroll
                for (int r = 0; r < 4; ++r) O[d][r] *= alpha[r];

            // P -> LDS (wave-private 16-row stripe; no barrier needed)
            #pragma unroll
            for (int ct = 0; ct < 4; ++ct)
                #pragma unroll
                for (int r = 0; r < 4; ++r)
                    QPs[(16 * wave + quad * 4 + r) * LDK + ct * 16 + l15] = f2bf(p[ct][r]);

            short8 pa0 = *(const short8*)(QPs + (16 * wave + l15) * LDK + 0  + quad * 8);
            short8 pa1 = *(const short8*)(QPs + (16 * wave + l15) * LDK + 32 + quad * 8);
            #pragma unroll
            for (int dt = 0; dt < 4; ++dt) {
                short8 vb0 = *(const short8*)(Vs + (dt * 16 + l15) * LDV + sl + 0  + quad * 8);
                short8 vb1 = *(const short8*)(Vs + (dt * 16 + l15) * LDV + sl + 32 + quad * 8);
                O[dt] = __builtin_amdgcn_mfma_f32_16x16x32_bf16(pa0, vb0, O[dt], 0, 0, 0);
                O[dt] = __builtin_amdgcn_mfma_f32_16x16x32_bf16(pa1, vb1, O[dt], 0, 0, 0);
            }
        }
    }

    #pragma unroll
    for (int r = 0; r < 4; ++r) {
        const float inv_l = 1.0f / l_run[r];
        const int t = t0 + 16 * wave + quad * 4 + r;
        #pragma unroll
        for (int dt = 0; dt < 4; ++dt)
            yb[(size_t)t * D_MODEL + h * HD + dt * 16 + l15] = f2bf(O[dt][r] * inv_l);
    }
}

// ---------------------------------------------------------------------------
// Kernel 3: output projection (bf16 MFMA, BK=64), fp32 out. grid=(8,16).
// ---------------------------------------------------------------------------
__global__ __launch_bounds__(256) void gemm_proj(
        const ushort_t* __restrict__ yb, const ushort_t* __restrict__ Wpb,
        float* __restrict__ out)
{
    const int row0 = blockIdx.y * 128;
    const int col0 = blockIdx.x * 128;

    __shared__ ushort_t As[128 * LDB];
    __shared__ ushort_t Bs[128 * LDB];

    const int tid = threadIdx.x;
    const int wave = tid >> 6, lane = tid & 63;
    const int wm = wave >> 1, wn = wave & 1;
    const int l15 = lane & 15, quad = lane >> 4;
    const int r_st = tid >> 1;
    const int c_st = (tid & 1) * 32;

    floatx4 acc[4][4];
    #pragma unroll
    for (int i = 0; i < 4; ++i)
        #pragma unroll
        for (int j = 0; j < 4; ++j)
            acc[i][j] = (floatx4){0.f, 0.f, 0.f, 0.f};

    for (int k0 = 0; k0 < D_MODEL; k0 += 64) {
        __syncthreads();
        cp16(As + r_st * LDB + c_st,      yb  + (size_t)(row0 + r_st) * D_MODEL + k0 + c_st);
        cp16(As + r_st * LDB + c_st + 16, yb  + (size_t)(row0 + r_st) * D_MODEL + k0 + c_st + 16);
        cp16(Bs + r_st * LDB + c_st,      Wpb + (size_t)(col0 + r_st) * D_MODEL + k0 + c_st);
        cp16(Bs + r_st * LDB + c_st + 16, Wpb + (size_t)(col0 + r_st) * D_MODEL + k0 + c_st + 16);
        __syncthreads();
        #pragma unroll
        for (int kh = 0; kh < 2; ++kh) {
            short8 a[4], b[4];
            #pragma unroll
            for (int i = 0; i < 4; ++i) {
                a[i] = *(const short8*)(As + (64 * wm + i * 16 + l15) * LDB + kh * 32 + quad * 8);
                b[i] = *(const short8*)(Bs + (64 * wn + i * 16 + l15) * LDB + kh * 32 + quad * 8);
            }
            #pragma unroll
            for (int i = 0; i < 4; ++i)
                #pragma unroll
                for (int j = 0; j < 4; ++j)
                    acc[i][j] = __builtin_amdgcn_mfma_f32_16x16x32_bf16(a[i], b[j], acc[i][j], 0, 0, 0);
        }
    }

    #pragma unroll
    for (int i = 0; i < 4; ++i)
        #pragma unroll
        for (int j = 0; j < 4; ++j) {
            const int t = row0 + 64 * wm + i * 16 + quad * 4;
            const int jj = col0 + 64 * wn + j * 16 + l15;
            #pragma unroll
            for (int r = 0; r < 4; ++r)
                out[(size_t)(t + r) * D_MODEL + jj] = acc[i][j][r];
        }
}

// ---------------------------------------------------------------------------
extern "C" void kernel_launch(void* const* d_in, const int* in_sizes, int n_in,
                              void* d_out, int out_size, void* d_ws, size_t ws_size,
                              hipStream_t stream) {
    (void)in_sizes; (void)n_in; (void)out_size; (void)ws_size;
    const float* x   = (const float*)d_in[0];
    const float* vi  = (const float*)d_in[1];
    const float* Wq  = (const float*)d_in[2];
    const float* Wk  = (const float*)d_in[3];
    const float* Wv  = (const float*)d_in[4];
    const float* Wp  = (const float*)d_in[5];
    const float* lam = (const float*)d_in[6];

    char* base = (char*)d_ws;                                  // 28 MiB used
    ushort_t* xb  = (ushort_t*)(base);                         // [ 0, 4) MiB
    ushort_t* wqb = (ushort_t*)(base + (size_t)4  * 1048576);  // [ 4, 6)
    ushort_t* wkb = (ushort_t*)(base + (size_t)6  * 1048576);  // [ 6, 8)
    ushort_t* wvb = (ushort_t*)(base + (size_t)8  * 1048576);  // [ 8,10)
    ushort_t* wpb = (ushort_t*)(base + (size_t)10 * 1048576);  // [10,12)
    ushort_t* qb  = (ushort_t*)(base + (size_t)12 * 1048576);  // [12,16)
    ushort_t* kb  = (ushort_t*)(base + (size_t)16 * 1048576);  // [16,20)
    ushort_t* vbt = (ushort_t*)(base + (size_t)20 * 1048576);  // [20,24)  [d][t]
    ushort_t* yb  = (ushort_t*)(base + (size_t)24 * 1048576);  // [24,28)
    float* out = (float*)d_out;

    to_bf16<<<dim3(786432 / 256), 256, 0, stream>>>(x, Wq, Wk, Wv, Wp, xb, wqb, wkb, wvb, wpb);
    gemm_qkv<<<dim3(8, 16, 3), 256, 0, stream>>>(xb, wqb, wkb, wvb, vi, lam, qb, kb, vbt);
    attn<<<dim3(32, 16), 256, 0, stream>>>(qb, kb, vbt, yb);
    gemm_proj<<<dim3(8, 16), 256, 0, stream>>>(yb, wpb, out);
}